// Round 15
// baseline (648.282 us; speedup 1.0000x reference)
//
#include <hip/hip_runtime.h>
#include <stdint.h>

#define NN 100000
#define EE 3200000
#define DD 128
#define GG 64
#define CC 4
#define LLAYERS 3
#define KLIN 2
#define BN_EPS 1e-5f

#define BSH 8                                   // 256 nodes per bucket
#define NB ((NN + 255) >> BSH)                  // 391 buckets
#define CH 4096                                 // edge chunk for hist/scatter
#define NH ((EE + CH - 1) / CH)                 // 782 chunks
#define STAGE_CAP 10240

#define HSP 136   // bf16 LDS row pad (272 B: 16B-aligned rows, bank shift 4)

typedef unsigned short u16;
typedef unsigned int u32;
typedef short bf16x8 __attribute__((ext_vector_type(8)));
typedef float f32x4 __attribute__((ext_vector_type(4)));

__device__ __forceinline__ float bflo(u32 u){ return __uint_as_float(u << 16); }
__device__ __forceinline__ float bfhi(u32 u){ return __uint_as_float(u & 0xffff0000u); }
__device__ __forceinline__ u16 f2bf(float f){
  u32 u = __float_as_uint(f);
  u32 r = u + 0x7fffu + ((u >> 16) & 1u);   // RNE
  return (u16)(r >> 16);
}

// ---------------- merged: bucket histogram (blocks < NH) + x cast (rest) ----------------
__global__ __launch_bounds__(256) void hist_cast(const int* __restrict__ dst,
                                                 int* __restrict__ bcount,
                                                 const float4* __restrict__ x,
                                                 uint4* __restrict__ h){
  __shared__ int lh[NB];
  if (blockIdx.x < NH) {
    for (int i = threadIdx.x; i < NB; i += 256) lh[i] = 0;
    __syncthreads();
    const int b0 = blockIdx.x * CH;
    const int cnt = min(CH, EE - b0);
    const int4* d4 = (const int4*)(dst + b0);
    const int n4 = cnt >> 2;
    for (int i = threadIdx.x; i < n4; i += 256) {
      int4 v = d4[i];
      atomicAdd(&lh[v.x >> BSH], 1);
      atomicAdd(&lh[v.y >> BSH], 1);
      atomicAdd(&lh[v.z >> BSH], 1);
      atomicAdd(&lh[v.w >> BSH], 1);
    }
    for (int i = (n4 << 2) + threadIdx.x; i < cnt; i += 256)
      atomicAdd(&lh[dst[b0 + i] >> BSH], 1);
    __syncthreads();
    for (int i = threadIdx.x; i < NB; i += 256)
      if (lh[i]) atomicAdd(&bcount[i], lh[i]);
  } else {
    int i = (blockIdx.x - NH) * 256 + threadIdx.x;   // 8 f32 per thread
    if (i < NN*DD/8) {
      float4 a = x[2*i], b = x[2*i+1];
      uint4 o;
      o.x = (u32)f2bf(a.x) | ((u32)f2bf(a.y) << 16);
      o.y = (u32)f2bf(a.z) | ((u32)f2bf(a.w) << 16);
      o.z = (u32)f2bf(b.x) | ((u32)f2bf(b.y) << 16);
      o.w = (u32)f2bf(b.z) | ((u32)f2bf(b.w) << 16);
      h[i] = o;
    }
  }
}

// ---------------- merged: scan (block 0) + W swizzle/BN fold (blocks 1..6) ----------------
__global__ __launch_bounds__(512) void scan_prep(const int* __restrict__ bcount,
    int* __restrict__ bofs, int* __restrict__ gcur, int* __restrict__ row_start,
    const float* __restrict__ Ws, const float* __restrict__ bs,
    const float* __restrict__ gammas, const float* __restrict__ betas,
    const float* __restrict__ means, const float* __restrict__ vars,
    u16* __restrict__ Wt6, float* __restrict__ scale6, float* __restrict__ shift6){
  __shared__ float WS[64 * DD];   // 32 KB staging
  __shared__ int s[512];
  const int t = threadIdx.x;
  if (blockIdx.x == 0) {
    int v = (t < NB) ? bcount[t] : 0;
    s[t] = v; __syncthreads();
    for (int off = 1; off < 512; off <<= 1) {
      int u = (t >= off) ? s[t - off] : 0;
      __syncthreads();
      s[t] += u;
      __syncthreads();
    }
    if (t < NB) { int e = s[t] - v; bofs[t] = e; gcur[t] = e; }
    if (t == 0) row_start[NN] = EE;
  } else {
    const int sl = blockIdx.x - 1;   // sublayer 0..5
    const float* W = Ws + (size_t)sl * DD * DD;
    u16* Wt = Wt6 + (size_t)sl * DD * DD;
    if (t < DD) {
      float sc = gammas[sl*DD+t] * rsqrtf(vars[sl*DD+t] + BN_EPS);
      scale6[sl*DD+t] = sc;
      shift6[sl*DD+t] = (bs[sl*DD+t] - means[sl*DD+t]) * sc + betas[sl*DD+t];
    }
    #pragma unroll
    for (int p = 0; p < 2; ++p) {
      __syncthreads();
      const float4* srcp = (const float4*)(W + p * 64 * DD);
      float4* dstp = (float4*)WS;
      for (int i = t; i < 64 * DD / 4; i += 512) dstp[i] = srcp[i];
      __syncthreads();
      for (int f = t; f < DD*DD; f += 512) {
        int j = f & 7, lane = (f >> 3) & 63, ks = (f >> 9) & 3, ct = f >> 11;
        int k = ks*32 + (lane >> 4)*8 + j;
        if ((k >> 6) == p)
          Wt[f] = f2bf(WS[(k & 63)*DD + ct*16 + (lane & 15)]);
      }
    }
  }
}

// ---------------- bucket scatter (packed rec: src<<8 | dst&255) ----------------
__global__ __launch_bounds__(256) void bucket_scatter(const int* __restrict__ src,
                                                      const int* __restrict__ dst,
                                                      int* __restrict__ gcur,
                                                      u32* __restrict__ rec){
  __shared__ int lh[NB];
  __shared__ int lbase[NB];
  const int b0 = blockIdx.x * CH;
  const int cnt = min(CH, EE - b0);
  const int n4 = cnt >> 2;
  const int4* s4 = (const int4*)(src + b0);
  const int4* d4 = (const int4*)(dst + b0);
  for (int i = threadIdx.x; i < NB; i += 256) lh[i] = 0;
  __syncthreads();
  for (int i = threadIdx.x; i < n4; i += 256) {
    int4 v = d4[i];
    atomicAdd(&lh[v.x >> BSH], 1);
    atomicAdd(&lh[v.y >> BSH], 1);
    atomicAdd(&lh[v.z >> BSH], 1);
    atomicAdd(&lh[v.w >> BSH], 1);
  }
  for (int i = (n4 << 2) + threadIdx.x; i < cnt; i += 256)
    atomicAdd(&lh[dst[b0 + i] >> BSH], 1);
  __syncthreads();
  for (int i = threadIdx.x; i < NB; i += 256) {
    int c = lh[i];
    lbase[i] = c ? atomicAdd(&gcur[i], c) : 0;
    lh[i] = 0;   // reuse as local cursor
  }
  __syncthreads();
  for (int i = threadIdx.x; i < n4; i += 256) {
    int4 ss = s4[i], dd = d4[i];
    {
      int bk = dd.x >> BSH;
      int pos = lbase[bk] + atomicAdd(&lh[bk], 1);
      rec[pos] = ((u32)ss.x << BSH) | (u32)(dd.x & 255);
    }
    {
      int bk = dd.y >> BSH;
      int pos = lbase[bk] + atomicAdd(&lh[bk], 1);
      rec[pos] = ((u32)ss.y << BSH) | (u32)(dd.y & 255);
    }
    {
      int bk = dd.z >> BSH;
      int pos = lbase[bk] + atomicAdd(&lh[bk], 1);
      rec[pos] = ((u32)ss.z << BSH) | (u32)(dd.z & 255);
    }
    {
      int bk = dd.w >> BSH;
      int pos = lbase[bk] + atomicAdd(&lh[bk], 1);
      rec[pos] = ((u32)ss.w << BSH) | (u32)(dd.w & 255);
    }
  }
  for (int i = (n4 << 2) + threadIdx.x; i < cnt; i += 256) {
    int d = dst[b0 + i];
    int bk = d >> BSH;
    int pos = lbase[bk] + atomicAdd(&lh[bk], 1);
    rec[pos] = ((u32)src[b0 + i] << BSH) | (u32)(d & 255);
  }
}

// ---------------- bucket emit: group by node, then wave-bitonic sort by src ----------------
// Sorted adjacency lists align the chip-wide gather sweep (L2/L3 locality,
// measured FETCH 369->330 MB, gin -9 us/layer). Sort via 64-lane bitonic
// network in registers (__shfl_xor, 21 steps) — one wave per node, zero LDS
// traffic, no divergent serial chains. deg>64 (P~1e-8) falls back unsorted
// (sort is perf-only; correctness independent of order).
__global__ __launch_bounds__(256) void bucket_emit(const u32* __restrict__ rec,
                                                   const int* __restrict__ bofs,
                                                   const int* __restrict__ bcount,
                                                   int* __restrict__ row_start,
                                                   int* __restrict__ sorted_src){
  __shared__ int cnt[256];
  __shared__ int ofs[256];
  __shared__ int segs[257];       // segment starts (in-bucket), +1 sentinel
  __shared__ int stage[STAGE_CAP];
  const int b = blockIdx.x, t = threadIdx.x;
  const int nodebase = b << BSH;
  const int nlocal = min(256, NN - nodebase);
  const int ebeg = bofs[b];
  const int ecnt = bcount[b];
  cnt[t] = 0;
  __syncthreads();
  for (int i = t; i < ecnt; i += 256)
    atomicAdd(&cnt[rec[ebeg + i] & 255u], 1);
  __syncthreads();
  const int deg0 = cnt[t];
  ofs[t] = deg0;
  __syncthreads();
  for (int off = 1; off < 256; off <<= 1) {
    int u = (t >= off) ? ofs[t - off] : 0;
    __syncthreads();
    ofs[t] += u;
    __syncthreads();
  }
  const int excl = ofs[t] - deg0;
  if (t < nlocal) row_start[nodebase + t] = ebeg + excl;
  segs[t] = excl;
  cnt[t] = excl;   // cursor
  if (t == 0) segs[256] = ecnt;
  __syncthreads();

  if (ecnt <= STAGE_CAP) {
    // group packed records by node into stage
    for (int i = t; i < ecnt; i += 256) {
      u32 r = rec[ebeg + i];
      int pos = atomicAdd(&cnt[r & 255u], 1);
      stage[pos] = (int)r;
    }
    __syncthreads();
    // wave w sorts nodes [w*64, w*64+64): 64-lane bitonic in registers
    const int wave = t >> 6, lane = t & 63;
    for (int n = wave * 64; n < wave * 64 + 64; ++n) {
      const int s = segs[n], e2 = segs[n + 1];
      const int deg = e2 - s;
      if (deg <= 0) continue;
      if (deg > 64) {   // statistically unreachable fallback: unsorted copy
        for (int q = s + lane; q < e2; q += 64)
          sorted_src[ebeg + q] = stage[q] >> BSH;
        continue;
      }
      int v = (lane < deg) ? (stage[s + lane] >> BSH) : 0x7fffffff;
      #pragma unroll
      for (int k = 2; k <= 64; k <<= 1) {
        #pragma unroll
        for (int j = k >> 1; j > 0; j >>= 1) {
          int p = __shfl_xor(v, j);
          bool up = ((lane & k) == 0) || (k == 64);  // final merge ascending
          bool lower = ((lane & j) == 0);
          bool takeMin = (up == lower);
          v = takeMin ? min(v, p) : max(v, p);
        }
      }
      if (lane < deg) sorted_src[ebeg + s + lane] = v;
    }
  } else {
    // fallback (statistically unreachable): unsorted direct scatter
    for (int i = t; i < ecnt; i += 256) {
      u32 r = rec[ebeg + i];
      int pos = atomicAdd(&cnt[r & 255u], 1);
      sorted_src[ebeg + pos] = (int)(r >> BSH);
    }
  }
}

// ---------------- fused GIN layer: gather -> MLP1 -> MLP2 ----------------
// Block = 16 nodes (grid 6250): one thread per (node,l16) in the gather, no
// serial node loop. The 4 waves cooperate on the 16x128 tile: each wave does
// 2 of 8 col-tiles per MFMA phase; Y1 via shared LDS. 100000 = 6250*16.
__global__ __launch_bounds__(256) void gin_layer(
    const u16* __restrict__ H, u16* __restrict__ O,
    const int* __restrict__ row_start, const int* __restrict__ sorted_src,
    const u16* __restrict__ W1t, const float* __restrict__ scale1, const float* __restrict__ shift1,
    const u16* __restrict__ W2t, const float* __restrict__ scale2, const float* __restrict__ shift2)
{
  __shared__ u16 HS[16][HSP];     // agg rows (bf16)
  __shared__ u16 YS[16][HSP];     // Y1 rows (bf16)

  const int tid = threadIdx.x;
  const int base = blockIdx.x * 16;
  const uint4* hp = (const uint4*)H;

  // ---- phase 0: gather — one thread per (node, 16B chunk), x4 unrolled ----
  {
    const int g = tid >> 4, l16 = tid & 15;
    const int node = base + g;
    uint4 v = hp[(size_t)node*16 + l16];   // self term (eps=0)
    float a0=bflo(v.x), a1=bfhi(v.x), a2=bflo(v.y), a3=bfhi(v.y);
    float a4=bflo(v.z), a5=bfhi(v.z), a6=bflo(v.w), a7=bfhi(v.w);
    float b0=0.f,b1=0.f,b2=0.f,b3=0.f,b4=0.f,b5=0.f,b6=0.f,b7=0.f;
    float c0=0.f,c1=0.f,c2=0.f,c3=0.f,c4=0.f,c5=0.f,c6=0.f,c7=0.f;
    float d0=0.f,d1=0.f,d2=0.f,d3=0.f,d4=0.f,d5=0.f,d6=0.f,d7=0.f;
    int e = row_start[node];
    const int end = row_start[node + 1];
    for (; e + 3 < end; e += 4) {          // 4 row-loads in flight
      int s0 = sorted_src[e],   s1 = sorted_src[e+1];
      int s2 = sorted_src[e+2], s3 = sorted_src[e+3];
      uint4 u0 = hp[(size_t)s0*16 + l16];
      uint4 u1 = hp[(size_t)s1*16 + l16];
      uint4 u2 = hp[(size_t)s2*16 + l16];
      uint4 u3 = hp[(size_t)s3*16 + l16];
      a0 += bflo(u0.x); a1 += bfhi(u0.x); a2 += bflo(u0.y); a3 += bfhi(u0.y);
      a4 += bflo(u0.z); a5 += bfhi(u0.z); a6 += bflo(u0.w); a7 += bfhi(u0.w);
      b0 += bflo(u1.x); b1 += bfhi(u1.x); b2 += bflo(u1.y); b3 += bfhi(u1.y);
      b4 += bflo(u1.z); b5 += bfhi(u1.z); b6 += bflo(u1.w); b7 += bfhi(u1.w);
      c0 += bflo(u2.x); c1 += bfhi(u2.x); c2 += bflo(u2.y); c3 += bfhi(u2.y);
      c4 += bflo(u2.z); c5 += bfhi(u2.z); c6 += bflo(u2.w); c7 += bfhi(u2.w);
      d0 += bflo(u3.x); d1 += bfhi(u3.x); d2 += bflo(u3.y); d3 += bfhi(u3.y);
      d4 += bflo(u3.z); d5 += bfhi(u3.z); d6 += bflo(u3.w); d7 += bfhi(u3.w);
    }
    for (; e < end; ++e) {
      int s0 = sorted_src[e];
      uint4 u0 = hp[(size_t)s0*16 + l16];
      a0 += bflo(u0.x); a1 += bfhi(u0.x); a2 += bflo(u0.y); a3 += bfhi(u0.y);
      a4 += bflo(u0.z); a5 += bfhi(u0.z); a6 += bflo(u0.w); a7 += bfhi(u0.w);
    }
    a0 += b0+c0+d0; a1 += b1+c1+d1; a2 += b2+c2+d2; a3 += b3+c3+d3;
    a4 += b4+c4+d4; a5 += b5+c5+d5; a6 += b6+c6+d6; a7 += b7+c7+d7;
    uint4 w;
    w.x = (u32)f2bf(a0) | ((u32)f2bf(a1) << 16);
    w.y = (u32)f2bf(a2) | ((u32)f2bf(a3) << 16);
    w.z = (u32)f2bf(a4) | ((u32)f2bf(a5) << 16);
    w.w = (u32)f2bf(a6) | ((u32)f2bf(a7) << 16);
    *(uint4*)&HS[g][l16*8] = w;
  }
  __syncthreads();

  const int wave = tid >> 6, lane = tid & 63;
  const int ln15 = lane & 15, quad = lane >> 4;

  // ---- phase 1: Y1 = relu(bn1(HS @ W1)) -> YS; wave handles col-tiles 2w,2w+1 ----
  {
    bf16x8 af[4];
    #pragma unroll
    for (int ks = 0; ks < 4; ++ks)
      af[ks] = *(const bf16x8*)&HS[ln15][ks*32 + quad*8];
    f32x4 acc[2];
    acc[0] = (f32x4){0.f,0.f,0.f,0.f};
    acc[1] = (f32x4){0.f,0.f,0.f,0.f};
    #pragma unroll
    for (int ks = 0; ks < 4; ++ks) {
      #pragma unroll
      for (int j = 0; j < 2; ++j) {
        const int ct = wave*2 + j;
        bf16x8 bf = *(const bf16x8*)(W1t + (((ct*4 + ks)*64 + lane) << 3));
        acc[j] = __builtin_amdgcn_mfma_f32_16x16x32_bf16(af[ks], bf, acc[j], 0, 0, 0);
      }
    }
    #pragma unroll
    for (int j = 0; j < 2; ++j) {
      const int col = (wave*2 + j)*16 + ln15;
      const float sc = scale1[col], sh = shift1[col];
      #pragma unroll
      for (int reg = 0; reg < 4; ++reg)
        YS[quad*4 + reg][col] = f2bf(fmaxf(acc[j][reg]*sc + sh, 0.f));
    }
  }
  __syncthreads();

  // ---- phase 2: Y2 = relu(bn2(YS @ W2)) -> global ----
  {
    bf16x8 af[4];
    #pragma unroll
    for (int ks = 0; ks < 4; ++ks)
      af[ks] = *(const bf16x8*)&YS[ln15][ks*32 + quad*8];
    f32x4 acc[2];
    acc[0] = (f32x4){0.f,0.f,0.f,0.f};
    acc[1] = (f32x4){0.f,0.f,0.f,0.f};
    #pragma unroll
    for (int ks = 0; ks < 4; ++ks) {
      #pragma unroll
      for (int j = 0; j < 2; ++j) {
        const int ct = wave*2 + j;
        bf16x8 bf = *(const bf16x8*)(W2t + (((ct*4 + ks)*64 + lane) << 3));
        acc[j] = __builtin_amdgcn_mfma_f32_16x16x32_bf16(af[ks], bf, acc[j], 0, 0, 0);
      }
    }
    #pragma unroll
    for (int j = 0; j < 2; ++j) {
      const int col = (wave*2 + j)*16 + ln15;
      const float sc = scale2[col], sh = shift2[col];
      #pragma unroll
      for (int reg = 0; reg < 4; ++reg) {
        const int row = base + quad*4 + reg;
        O[(size_t)row * DD + col] = f2bf(fmaxf(acc[j][reg]*sc + sh, 0.f));
      }
    }
  }
}

// ---------------- fused segmented max-pool + classify (batch sorted), 512 thr ----------------
__global__ __launch_bounds__(512) void pool_classify(const u16* __restrict__ h,
    const int* __restrict__ batch, const float* __restrict__ lw,
    const float* __restrict__ lb, float* __restrict__ out){
  __shared__ float red[512 * 8];
  __shared__ float P[DD];
  __shared__ int range[2];
  const int g = blockIdx.x, tid = threadIdx.x;
  if (tid < 2) {
    int target = g + tid;
    int lo = 0, hi = NN;
    while (lo < hi) { int mid = (lo + hi) >> 1; if (batch[mid] < target) lo = mid + 1; else hi = mid; }
    range[tid] = lo;
  }
  __syncthreads();
  const int beg = range[0], end = range[1];
  const int rg = tid >> 4, l16 = tid & 15;   // 32 row-groups x 16 cols
  const uint4* hp = (const uint4*)h;
  float m0=0.f,m1=0.f,m2=0.f,m3=0.f,m4=0.f,m5=0.f,m6=0.f,m7=0.f;  // h >= 0
  for (int n = beg + rg; n < end; n += 32) {
    uint4 u = hp[(size_t)n * 16 + l16];
    m0 = fmaxf(m0, bflo(u.x)); m1 = fmaxf(m1, bfhi(u.x));
    m2 = fmaxf(m2, bflo(u.y)); m3 = fmaxf(m3, bfhi(u.y));
    m4 = fmaxf(m4, bflo(u.z)); m5 = fmaxf(m5, bfhi(u.z));
    m6 = fmaxf(m6, bflo(u.w)); m7 = fmaxf(m7, bfhi(u.w));
  }
  float* r = &red[tid * 8];
  r[0]=m0; r[1]=m1; r[2]=m2; r[3]=m3; r[4]=m4; r[5]=m5; r[6]=m6; r[7]=m7;
  __syncthreads();
  #pragma unroll
  for (int off = 16; off > 0; off >>= 1) {
    if (rg < off) {
      float* o = &red[(tid + off*16) * 8];
      #pragma unroll
      for (int i = 0; i < 8; ++i) r[i] = fmaxf(r[i], o[i]);
    }
    __syncthreads();
  }
  if (rg == 0) {
    #pragma unroll
    for (int i = 0; i < 8; ++i) P[l16*8 + i] = r[i];
  }
  __syncthreads();
  // classify with wave 0 (pooled row lives in LDS)
  if (tid < 64) {
    float x0 = P[tid];
    float x1 = P[tid + 64];
    float4 wA = *(const float4*)(lw + tid*4);
    float4 wB = *(const float4*)(lw + (tid+64)*4);
    float a0 = x0*wA.x + x1*wB.x;
    float a1 = x0*wA.y + x1*wB.y;
    float a2 = x0*wA.z + x1*wB.z;
    float a3 = x0*wA.w + x1*wB.w;
    #pragma unroll
    for (int off = 32; off > 0; off >>= 1) {
      a0 += __shfl_down(a0, off);
      a1 += __shfl_down(a1, off);
      a2 += __shfl_down(a2, off);
      a3 += __shfl_down(a3, off);
    }
    if (tid == 0) {
      float l0 = a0 + lb[0];
      float l1 = a1 + lb[1];
      float l2 = a2 + lb[2];
      float l3 = a3 + lb[3];
      float m = fmaxf(fmaxf(l0,l1), fmaxf(l2,l3));
      float s = expf(l0-m)+expf(l1-m)+expf(l2-m)+expf(l3-m);
      float lse = logf(s) + m;
      out[g*4+0] = l0 - lse;
      out[g*4+1] = l1 - lse;
      out[g*4+2] = l2 - lse;
      out[g*4+3] = l3 - lse;
    }
  }
}

extern "C" void kernel_launch(void* const* d_in, const int* in_sizes, int n_in,
                              void* d_out, int out_size, void* d_ws, size_t ws_size,
                              hipStream_t stream) {
  const float* x     = (const float*)d_in[0];
  const int* ei      = (const int*)d_in[1];
  const int* batch   = (const int*)d_in[2];
  const float* Ws    = (const float*)d_in[3];
  const float* bs    = (const float*)d_in[4];
  const float* gammas= (const float*)d_in[5];
  const float* betas = (const float*)d_in[6];
  const float* means = (const float*)d_in[7];
  const float* vars  = (const float*)d_in[8];
  const float* lw    = (const float*)d_in[9];
  const float* lb    = (const float*)d_in[10];
  float* out = (float*)d_out;

  // workspace layout (rec has its own region so cast can run before CSR)
  u16* hA = (u16*)d_ws;                                 // N*D bf16
  u16* hB = hA + (size_t)NN * DD;                       // N*D bf16
  float* scale6 = (float*)(hB + (size_t)NN * DD);       // 6*D
  float* shift6 = scale6 + 6 * DD;                      // 6*D
  int* row_start  = (int*)(shift6 + 6 * DD);            // N+1
  int* bcount     = row_start + NN + 2;                 // NB
  int* bofs       = bcount + NB;                        // NB
  int* gcur       = bofs + NB;                          // NB
  int* sorted_src = gcur + NB + 3;                      // E
  u32* rec        = (u32*)(sorted_src + EE);            // E packed records
  u16* Wt6 = (u16*)(((uintptr_t)(rec + EE) + 63) & ~(uintptr_t)63);  // 6*D*D bf16

  const int* srcIdx = ei;
  const int* dstIdx = ei + EE;

  // ---- CSR build + prologue (hist overlapped with x-cast; prep with scan) ----
  hipMemsetAsync(bcount, 0, NB * sizeof(int), stream);
  hist_cast<<<NH + (NN*DD/8 + 255)/256, 256, 0, stream>>>(
      dstIdx, bcount, (const float4*)x, (uint4*)hA);
  scan_prep<<<7, 512, 0, stream>>>(bcount, bofs, gcur, row_start,
      Ws, bs, gammas, betas, means, vars, Wt6, scale6, shift6);
  bucket_scatter<<<NH, 256, 0, stream>>>(srcIdx, dstIdx, gcur, rec);
  bucket_emit<<<NB, 256, 0, stream>>>(rec, bofs, bcount, row_start, sorted_src);

  // ---- 3 fused GIN layers (16 nodes/block) ----
  u16* cur = hA;
  u16* tmp = hB;
  const int layer_grid = NN / 16;   // 6250
  for (int l = 0; l < LLAYERS; ++l) {
    int s0 = l*KLIN + 0, s1 = l*KLIN + 1;
    gin_layer<<<layer_grid, 256, 0, stream>>>(cur, tmp, row_start, sorted_src,
        Wt6 + (size_t)s0*DD*DD, scale6 + s0*DD, shift6 + s0*DD,
        Wt6 + (size_t)s1*DD*DD, scale6 + s1*DD, shift6 + s1*DD);
    u16* t = cur; cur = tmp; tmp = t;   // h now in cur
  }

  // ---- fused pool + classify ----
  pool_classify<<<GG, 512, 0, stream>>>(cur, batch, lw, lb, out);
}

// Round 16
// 611.928 us; speedup vs baseline: 1.0594x; 1.0594x over previous
//
#include <hip/hip_runtime.h>
#include <stdint.h>

#define NN 100000
#define EE 3200000
#define DD 128
#define GG 64
#define CC 4
#define LLAYERS 3
#define KLIN 2
#define BN_EPS 1e-5f

#define BSH 8                                   // 256 nodes per bucket
#define NB ((NN + 255) >> BSH)                  // 391 buckets
#define CHUNK3 8192
#define NBLK3 ((EE + CHUNK3 - 1) / CHUNK3)      // 391
#define STAGE_CAP 10240

#define HSP 136   // bf16 LDS row pad (272 B: 16B-aligned rows, bank shift 4)

typedef unsigned short u16;
typedef unsigned int u32;
typedef short bf16x8 __attribute__((ext_vector_type(8)));
typedef float f32x4 __attribute__((ext_vector_type(4)));

__device__ __forceinline__ float bflo(u32 u){ return __uint_as_float(u << 16); }
__device__ __forceinline__ float bfhi(u32 u){ return __uint_as_float(u & 0xffff0000u); }
__device__ __forceinline__ u16 f2bf(float f){
  u32 u = __float_as_uint(f);
  u32 r = u + 0x7fffu + ((u >> 16) & 1u);   // RNE
  return (u16)(r >> 16);
}

// ---------------- bucketed CSR build (counting sort by dst) ----------------
// rec packed: (src << 8) | (dst & 255)  -- src < 2^17, dstlocal < 2^8

__global__ __launch_bounds__(256) void bucket_hist(const int* __restrict__ dst,
                                                   int* __restrict__ bcount){
  __shared__ int lh[NB];
  for (int i = threadIdx.x; i < NB; i += 256) lh[i] = 0;
  __syncthreads();
  const int b0 = blockIdx.x * CHUNK3;
  const int cnt = min(CHUNK3, EE - b0);
  const int4* d4 = (const int4*)(dst + b0);
  const int n4 = cnt >> 2;
  for (int i = threadIdx.x; i < n4; i += 256) {
    int4 v = d4[i];
    atomicAdd(&lh[v.x >> BSH], 1);
    atomicAdd(&lh[v.y >> BSH], 1);
    atomicAdd(&lh[v.z >> BSH], 1);
    atomicAdd(&lh[v.w >> BSH], 1);
  }
  for (int i = (n4 << 2) + threadIdx.x; i < cnt; i += 256)
    atomicAdd(&lh[dst[b0 + i] >> BSH], 1);
  __syncthreads();
  for (int i = threadIdx.x; i < NB; i += 256)
    if (lh[i]) atomicAdd(&bcount[i], lh[i]);
}

__global__ __launch_bounds__(512) void bucket_scan(const int* __restrict__ bcount,
                                                   int* __restrict__ bofs,
                                                   int* __restrict__ gcur,
                                                   int* __restrict__ row_start){
  __shared__ int s[512];
  int t = threadIdx.x;
  int v = (t < NB) ? bcount[t] : 0;
  s[t] = v; __syncthreads();
  for (int off = 1; off < 512; off <<= 1) {
    int u = (t >= off) ? s[t - off] : 0;
    __syncthreads();
    s[t] += u;
    __syncthreads();
  }
  if (t < NB) { int e = s[t] - v; bofs[t] = e; gcur[t] = e; }
  if (t == 0) row_start[NN] = EE;
}

__global__ __launch_bounds__(256) void bucket_scatter(const int* __restrict__ src,
                                                      const int* __restrict__ dst,
                                                      int* __restrict__ gcur,
                                                      u32* __restrict__ rec){
  __shared__ int lh[NB];
  __shared__ int lbase[NB];
  const int b0 = blockIdx.x * CHUNK3;
  const int cnt = min(CHUNK3, EE - b0);
  const int n4 = cnt >> 2;
  const int4* s4 = (const int4*)(src + b0);
  const int4* d4 = (const int4*)(dst + b0);
  for (int i = threadIdx.x; i < NB; i += 256) lh[i] = 0;
  __syncthreads();
  for (int i = threadIdx.x; i < n4; i += 256) {
    int4 v = d4[i];
    atomicAdd(&lh[v.x >> BSH], 1);
    atomicAdd(&lh[v.y >> BSH], 1);
    atomicAdd(&lh[v.z >> BSH], 1);
    atomicAdd(&lh[v.w >> BSH], 1);
  }
  for (int i = (n4 << 2) + threadIdx.x; i < cnt; i += 256)
    atomicAdd(&lh[dst[b0 + i] >> BSH], 1);
  __syncthreads();
  for (int i = threadIdx.x; i < NB; i += 256) {
    int c = lh[i];
    lbase[i] = c ? atomicAdd(&gcur[i], c) : 0;
    lh[i] = 0;   // reuse as local cursor
  }
  __syncthreads();
  for (int i = threadIdx.x; i < n4; i += 256) {
    int4 ss = s4[i], dd = d4[i];
    {
      int bk = dd.x >> BSH;
      int pos = lbase[bk] + atomicAdd(&lh[bk], 1);
      rec[pos] = ((u32)ss.x << BSH) | (u32)(dd.x & 255);
    }
    {
      int bk = dd.y >> BSH;
      int pos = lbase[bk] + atomicAdd(&lh[bk], 1);
      rec[pos] = ((u32)ss.y << BSH) | (u32)(dd.y & 255);
    }
    {
      int bk = dd.z >> BSH;
      int pos = lbase[bk] + atomicAdd(&lh[bk], 1);
      rec[pos] = ((u32)ss.z << BSH) | (u32)(dd.z & 255);
    }
    {
      int bk = dd.w >> BSH;
      int pos = lbase[bk] + atomicAdd(&lh[bk], 1);
      rec[pos] = ((u32)ss.w << BSH) | (u32)(dd.w & 255);
    }
  }
  for (int i = (n4 << 2) + threadIdx.x; i < cnt; i += 256) {
    int d = dst[b0 + i];
    int bk = d >> BSH;
    int pos = lbase[bk] + atomicAdd(&lh[bk], 1);
    rec[pos] = ((u32)src[b0 + i] << BSH) | (u32)(d & 255);
  }
}

__global__ __launch_bounds__(256) void bucket_emit(const u32* __restrict__ rec,
                                                   const int* __restrict__ bofs,
                                                   const int* __restrict__ bcount,
                                                   int* __restrict__ row_start,
                                                   int* __restrict__ sorted_src){
  __shared__ int cnt[256];
  __shared__ int ofs[256];
  __shared__ int stage[STAGE_CAP];
  const int b = blockIdx.x, t = threadIdx.x;
  const int nodebase = b << BSH;
  const int nlocal = min(256, NN - nodebase);
  const int ebeg = bofs[b];
  const int ecnt = bcount[b];
  cnt[t] = 0;
  __syncthreads();
  for (int i = t; i < ecnt; i += 256)
    atomicAdd(&cnt[rec[ebeg + i] & 255u], 1);
  __syncthreads();
  int v = cnt[t];
  ofs[t] = v;
  __syncthreads();
  for (int off = 1; off < 256; off <<= 1) {
    int u = (t >= off) ? ofs[t - off] : 0;
    __syncthreads();
    ofs[t] += u;
    __syncthreads();
  }
  int excl = ofs[t] - v;
  if (t < nlocal) row_start[nodebase + t] = ebeg + excl;
  cnt[t] = excl;   // cursor
  __syncthreads();
  for (int i = t; i < ecnt; i += 256) {
    u32 r = rec[ebeg + i];
    int pos = atomicAdd(&cnt[r & 255u], 1);
    if (pos < STAGE_CAP) stage[pos] = (int)(r >> BSH);
    else sorted_src[ebeg + pos] = (int)(r >> BSH);   // overflow fallback
  }
  __syncthreads();
  int lim = min(ecnt, STAGE_CAP);
  for (int i = t; i < lim; i += 256)
    sorted_src[ebeg + i] = stage[i];
}

// ---------------- merged prep (W swizzle + BN fold) + x cast ----------------
// blocks 0..5: swizzle W_s into MFMA B-frag order; blocks 6..: cast x -> bf16
__global__ __launch_bounds__(256) void prep_cast_kernel(const float* __restrict__ Ws,
    const float* __restrict__ bs, const float* __restrict__ gammas,
    const float* __restrict__ betas, const float* __restrict__ means,
    const float* __restrict__ vars,
    u16* __restrict__ Wt6, float* __restrict__ scale6, float* __restrict__ shift6,
    const float4* __restrict__ x, uint4* __restrict__ h){
  if (blockIdx.x < 6) {
    const int s = blockIdx.x;
    const float* W = Ws + (size_t)s * DD * DD;
    u16* Wt = Wt6 + (size_t)s * DD * DD;
    const int t = threadIdx.x;
    if (t < DD) {
      float sc = gammas[s*DD+t] * rsqrtf(vars[s*DD+t] + BN_EPS);
      scale6[s*DD+t] = sc;
      shift6[s*DD+t] = (bs[s*DD+t] - means[s*DD+t]) * sc + betas[s*DD+t];
    }
    for (int f = t; f < DD*DD; f += 256) {
      int j = f & 7, lane = (f >> 3) & 63, ks = (f >> 9) & 3, ct = f >> 11;
      int k = ks*32 + (lane >> 4)*8 + j;
      int n = ct*16 + (lane & 15);
      Wt[f] = f2bf(W[k*DD + n]);
    }
  } else {
    int i = (blockIdx.x - 6) * 256 + threadIdx.x;   // 8 f32 per thread
    if (i < NN*DD/8) {
      float4 a = x[2*i], b = x[2*i+1];
      uint4 o;
      o.x = (u32)f2bf(a.x) | ((u32)f2bf(a.y) << 16);
      o.y = (u32)f2bf(a.z) | ((u32)f2bf(a.w) << 16);
      o.z = (u32)f2bf(b.x) | ((u32)f2bf(b.y) << 16);
      o.w = (u32)f2bf(b.z) | ((u32)f2bf(b.w) << 16);
      h[i] = o;
    }
  }
}

// ---------------- fused GIN layer: gather -> MLP1 -> MLP2 ----------------
// Block = 16 nodes (grid 6250): one thread per (node,l16) in the gather, no
// serial node loop. The 4 waves cooperate on the 16x128 tile: each wave does
// 2 of 8 col-tiles per MFMA phase; Y1 via shared LDS. 100000 = 6250*16.
__global__ __launch_bounds__(256) void gin_layer(
    const u16* __restrict__ H, u16* __restrict__ O,
    const int* __restrict__ row_start, const int* __restrict__ sorted_src,
    const u16* __restrict__ W1t, const float* __restrict__ scale1, const float* __restrict__ shift1,
    const u16* __restrict__ W2t, const float* __restrict__ scale2, const float* __restrict__ shift2)
{
  __shared__ u16 HS[16][HSP];     // agg rows (bf16)
  __shared__ u16 YS[16][HSP];     // Y1 rows (bf16)

  const int tid = threadIdx.x;
  const int base = blockIdx.x * 16;
  const uint4* hp = (const uint4*)H;

  // ---- phase 0: gather — one thread per (node, 16B chunk), x4 unrolled ----
  {
    const int g = tid >> 4, l16 = tid & 15;
    const int node = base + g;
    uint4 v = hp[(size_t)node*16 + l16];   // self term (eps=0)
    float a0=bflo(v.x), a1=bfhi(v.x), a2=bflo(v.y), a3=bfhi(v.y);
    float a4=bflo(v.z), a5=bfhi(v.z), a6=bflo(v.w), a7=bfhi(v.w);
    float b0=0.f,b1=0.f,b2=0.f,b3=0.f,b4=0.f,b5=0.f,b6=0.f,b7=0.f;
    float c0=0.f,c1=0.f,c2=0.f,c3=0.f,c4=0.f,c5=0.f,c6=0.f,c7=0.f;
    float d0=0.f,d1=0.f,d2=0.f,d3=0.f,d4=0.f,d5=0.f,d6=0.f,d7=0.f;
    int e = row_start[node];
    const int end = row_start[node + 1];
    for (; e + 3 < end; e += 4) {          // 4 row-loads in flight
      int s0 = sorted_src[e],   s1 = sorted_src[e+1];
      int s2 = sorted_src[e+2], s3 = sorted_src[e+3];
      uint4 u0 = hp[(size_t)s0*16 + l16];
      uint4 u1 = hp[(size_t)s1*16 + l16];
      uint4 u2 = hp[(size_t)s2*16 + l16];
      uint4 u3 = hp[(size_t)s3*16 + l16];
      a0 += bflo(u0.x); a1 += bfhi(u0.x); a2 += bflo(u0.y); a3 += bfhi(u0.y);
      a4 += bflo(u0.z); a5 += bfhi(u0.z); a6 += bflo(u0.w); a7 += bfhi(u0.w);
      b0 += bflo(u1.x); b1 += bfhi(u1.x); b2 += bflo(u1.y); b3 += bfhi(u1.y);
      b4 += bflo(u1.z); b5 += bfhi(u1.z); b6 += bflo(u1.w); b7 += bfhi(u1.w);
      c0 += bflo(u2.x); c1 += bfhi(u2.x); c2 += bflo(u2.y); c3 += bfhi(u2.y);
      c4 += bflo(u2.z); c5 += bfhi(u2.z); c6 += bflo(u2.w); c7 += bfhi(u2.w);
      d0 += bflo(u3.x); d1 += bfhi(u3.x); d2 += bflo(u3.y); d3 += bfhi(u3.y);
      d4 += bflo(u3.z); d5 += bfhi(u3.z); d6 += bflo(u3.w); d7 += bfhi(u3.w);
    }
    for (; e < end; ++e) {
      int s0 = sorted_src[e];
      uint4 u0 = hp[(size_t)s0*16 + l16];
      a0 += bflo(u0.x); a1 += bfhi(u0.x); a2 += bflo(u0.y); a3 += bfhi(u0.y);
      a4 += bflo(u0.z); a5 += bfhi(u0.z); a6 += bflo(u0.w); a7 += bfhi(u0.w);
    }
    a0 += b0+c0+d0; a1 += b1+c1+d1; a2 += b2+c2+d2; a3 += b3+c3+d3;
    a4 += b4+c4+d4; a5 += b5+c5+d5; a6 += b6+c6+d6; a7 += b7+c7+d7;
    uint4 w;
    w.x = (u32)f2bf(a0) | ((u32)f2bf(a1) << 16);
    w.y = (u32)f2bf(a2) | ((u32)f2bf(a3) << 16);
    w.z = (u32)f2bf(a4) | ((u32)f2bf(a5) << 16);
    w.w = (u32)f2bf(a6) | ((u32)f2bf(a7) << 16);
    *(uint4*)&HS[g][l16*8] = w;
  }
  __syncthreads();

  const int wave = tid >> 6, lane = tid & 63;
  const int ln15 = lane & 15, quad = lane >> 4;

  // ---- phase 1: Y1 = relu(bn1(HS @ W1)) -> YS; wave handles col-tiles 2w,2w+1 ----
  {
    bf16x8 af[4];
    #pragma unroll
    for (int ks = 0; ks < 4; ++ks)
      af[ks] = *(const bf16x8*)&HS[ln15][ks*32 + quad*8];
    f32x4 acc[2];
    acc[0] = (f32x4){0.f,0.f,0.f,0.f};
    acc[1] = (f32x4){0.f,0.f,0.f,0.f};
    #pragma unroll
    for (int ks = 0; ks < 4; ++ks) {
      #pragma unroll
      for (int j = 0; j < 2; ++j) {
        const int ct = wave*2 + j;
        bf16x8 bf = *(const bf16x8*)(W1t + (((ct*4 + ks)*64 + lane) << 3));
        acc[j] = __builtin_amdgcn_mfma_f32_16x16x32_bf16(af[ks], bf, acc[j], 0, 0, 0);
      }
    }
    #pragma unroll
    for (int j = 0; j < 2; ++j) {
      const int col = (wave*2 + j)*16 + ln15;
      const float sc = scale1[col], sh = shift1[col];
      #pragma unroll
      for (int reg = 0; reg < 4; ++reg)
        YS[quad*4 + reg][col] = f2bf(fmaxf(acc[j][reg]*sc + sh, 0.f));
    }
  }
  __syncthreads();

  // ---- phase 2: Y2 = relu(bn2(YS @ W2)) -> global ----
  {
    bf16x8 af[4];
    #pragma unroll
    for (int ks = 0; ks < 4; ++ks)
      af[ks] = *(const bf16x8*)&YS[ln15][ks*32 + quad*8];
    f32x4 acc[2];
    acc[0] = (f32x4){0.f,0.f,0.f,0.f};
    acc[1] = (f32x4){0.f,0.f,0.f,0.f};
    #pragma unroll
    for (int ks = 0; ks < 4; ++ks) {
      #pragma unroll
      for (int j = 0; j < 2; ++j) {
        const int ct = wave*2 + j;
        bf16x8 bf = *(const bf16x8*)(W2t + (((ct*4 + ks)*64 + lane) << 3));
        acc[j] = __builtin_amdgcn_mfma_f32_16x16x32_bf16(af[ks], bf, acc[j], 0, 0, 0);
      }
    }
    #pragma unroll
    for (int j = 0; j < 2; ++j) {
      const int col = (wave*2 + j)*16 + ln15;
      const float sc = scale2[col], sh = shift2[col];
      #pragma unroll
      for (int reg = 0; reg < 4; ++reg) {
        const int row = base + quad*4 + reg;
        O[(size_t)row * DD + col] = f2bf(fmaxf(acc[j][reg]*sc + sh, 0.f));
      }
    }
  }
}

// ---------------- fused segmented max-pool + classify (batch sorted) ----------------
__global__ __launch_bounds__(256) void pool_classify(const u16* __restrict__ h,
    const int* __restrict__ batch, const float* __restrict__ lw,
    const float* __restrict__ lb, float* __restrict__ out){
  __shared__ float red[256 * 8];
  __shared__ float P[DD];
  __shared__ int range[2];
  const int g = blockIdx.x, tid = threadIdx.x;
  if (tid < 2) {
    int target = g + tid;
    int lo = 0, hi = NN;
    while (lo < hi) { int mid = (lo + hi) >> 1; if (batch[mid] < target) lo = mid + 1; else hi = mid; }
    range[tid] = lo;
  }
  __syncthreads();
  const int beg = range[0], end = range[1];
  const int rg = tid >> 4, l16 = tid & 15;
  const uint4* hp = (const uint4*)h;
  float m0=0.f,m1=0.f,m2=0.f,m3=0.f,m4=0.f,m5=0.f,m6=0.f,m7=0.f;  // h >= 0
  for (int n = beg + rg; n < end; n += 16) {
    uint4 u = hp[(size_t)n * 16 + l16];
    m0 = fmaxf(m0, bflo(u.x)); m1 = fmaxf(m1, bfhi(u.x));
    m2 = fmaxf(m2, bflo(u.y)); m3 = fmaxf(m3, bfhi(u.y));
    m4 = fmaxf(m4, bflo(u.z)); m5 = fmaxf(m5, bfhi(u.z));
    m6 = fmaxf(m6, bflo(u.w)); m7 = fmaxf(m7, bfhi(u.w));
  }
  float* r = &red[tid * 8];
  r[0]=m0; r[1]=m1; r[2]=m2; r[3]=m3; r[4]=m4; r[5]=m5; r[6]=m6; r[7]=m7;
  __syncthreads();
  #pragma unroll
  for (int off = 8; off > 0; off >>= 1) {
    if (rg < off) {
      float* o = &red[(tid + off*16) * 8];
      #pragma unroll
      for (int i = 0; i < 8; ++i) r[i] = fmaxf(r[i], o[i]);
    }
    __syncthreads();
  }
  if (rg == 0) {
    #pragma unroll
    for (int i = 0; i < 8; ++i) P[l16*8 + i] = r[i];
  }
  __syncthreads();
  // classify with wave 0 (pooled row lives in LDS)
  if (tid < 64) {
    float x0 = P[tid];
    float x1 = P[tid + 64];
    float4 wA = *(const float4*)(lw + tid*4);
    float4 wB = *(const float4*)(lw + (tid+64)*4);
    float a0 = x0*wA.x + x1*wB.x;
    float a1 = x0*wA.y + x1*wB.y;
    float a2 = x0*wA.z + x1*wB.z;
    float a3 = x0*wA.w + x1*wB.w;
    #pragma unroll
    for (int off = 32; off > 0; off >>= 1) {
      a0 += __shfl_down(a0, off);
      a1 += __shfl_down(a1, off);
      a2 += __shfl_down(a2, off);
      a3 += __shfl_down(a3, off);
    }
    if (tid == 0) {
      float l0 = a0 + lb[0];
      float l1 = a1 + lb[1];
      float l2 = a2 + lb[2];
      float l3 = a3 + lb[3];
      float m = fmaxf(fmaxf(l0,l1), fmaxf(l2,l3));
      float s = expf(l0-m)+expf(l1-m)+expf(l2-m)+expf(l3-m);
      float lse = logf(s) + m;
      out[g*4+0] = l0 - lse;
      out[g*4+1] = l1 - lse;
      out[g*4+2] = l2 - lse;
      out[g*4+3] = l3 - lse;
    }
  }
}

extern "C" void kernel_launch(void* const* d_in, const int* in_sizes, int n_in,
                              void* d_out, int out_size, void* d_ws, size_t ws_size,
                              hipStream_t stream) {
  const float* x     = (const float*)d_in[0];
  const int* ei      = (const int*)d_in[1];
  const int* batch   = (const int*)d_in[2];
  const float* Ws    = (const float*)d_in[3];
  const float* bs    = (const float*)d_in[4];
  const float* gammas= (const float*)d_in[5];
  const float* betas = (const float*)d_in[6];
  const float* means = (const float*)d_in[7];
  const float* vars  = (const float*)d_in[8];
  const float* lw    = (const float*)d_in[9];
  const float* lb    = (const float*)d_in[10];
  float* out = (float*)d_out;

  // workspace layout
  u16* hA = (u16*)d_ws;                                 // N*D bf16 (aliased by rec in CSR build)
  u16* hB = hA + (size_t)NN * DD;                       // N*D bf16
  float* scale6 = (float*)(hB + (size_t)NN * DD);       // 6*D
  float* shift6 = scale6 + 6 * DD;                      // 6*D
  int* row_start  = (int*)(shift6 + 6 * DD);            // N+1
  int* bcount     = row_start + NN + 2;                 // NB
  int* bofs       = bcount + NB;                        // NB
  int* gcur       = bofs + NB;                          // NB
  int* sorted_src = gcur + NB + 3;                      // E
  u16* Wt6 = (u16*)(((uintptr_t)(sorted_src + EE) + 63) & ~(uintptr_t)63);  // 6*D*D bf16
  u32* rec = (u32*)hA;                                  // E packed records (dead before cast)

  const int* srcIdx = ei;
  const int* dstIdx = ei + EE;

  // ---- CSR build ----
  hipMemsetAsync(bcount, 0, NB * sizeof(int), stream);
  bucket_hist<<<NBLK3, 256, 0, stream>>>(dstIdx, bcount);
  bucket_scan<<<1, 512, 0, stream>>>(bcount, bofs, gcur, row_start);
  bucket_scatter<<<NBLK3, 256, 0, stream>>>(srcIdx, dstIdx, gcur, rec);
  bucket_emit<<<NB, 256, 0, stream>>>(rec, bofs, bcount, row_start, sorted_src);

  // ---- merged prep (W swizzle + BN fold) + x cast ----
  prep_cast_kernel<<<6 + (NN*DD/8 + 255)/256, 256, 0, stream>>>(
      Ws, bs, gammas, betas, means, vars, Wt6, scale6, shift6,
      (const float4*)x, (uint4*)hA);

  // ---- 3 fused GIN layers (16 nodes/block) ----
  u16* cur = hA;
  u16* tmp = hB;
  const int layer_grid = NN / 16;   // 6250
  for (int l = 0; l < LLAYERS; ++l) {
    int s0 = l*KLIN + 0, s1 = l*KLIN + 1;
    gin_layer<<<layer_grid, 256, 0, stream>>>(cur, tmp, row_start, sorted_src,
        Wt6 + (size_t)s0*DD*DD, scale6 + s0*DD, shift6 + s0*DD,
        Wt6 + (size_t)s1*DD*DD, scale6 + s1*DD, shift6 + s1*DD);
    u16* t = cur; cur = tmp; tmp = t;   // h now in cur
  }

  // ---- fused pool + classify ----
  pool_classify<<<GG, 256, 0, stream>>>(cur, batch, lw, lb, out);
}